// Round 16
// baseline (75.755 us; speedup 1.0000x reference)
//
#include <hip/hip_runtime.h>
#include <math.h>

#define NMOD 4
#define BB   8
#define NN   4096
#define MM   4608
#define TPB  256

// ---- fast path geometry ----
#define QPT      8                      // queries per thread (named scalars)
#define QPB      (TPB * QPT)            // 2048 queries per block
#define NXB      (NN / QPB)             // 2
#define SLICES   16
#define SLICE_M  (MM / SLICES)          // 288
#define CH       16                     // targets per chunk
#define CHP      (CH + 1)               // padded chunk stride (bank aliasing)
#define NCHUNK   (SLICE_M / CH)         // 18
#define NSUP     (NCHUNK / 3)           // 6 superchunks (3 chunks = 24 pairs)
#define TOTP     (SLICE_M / 2)          // 144 pairs
#define QCOUNT   (NMOD * BB * NN)       // 131072
#define NXBLK2   (NN / TPB)             // 16
#define NPART    (NMOD * BB * NXBLK2)   // 512
#define KEYB     ((size_t)SLICES * QCOUNT * 8)   // 16.78 MB
#define WS_NEED  (KEYB + (size_t)NPART * 4)

typedef float v4f __attribute__((ext_vector_type(4)));

static __device__ __forceinline__ float min3f(float a, float b, float c) {
    float d;
    asm("v_min3_f32 %0, %1, %2, %3" : "=v"(d) : "v"(a), "v"(b), "v"(c));
    return d;
}

// immovable LDS read: compiler cannot re-sink it to the use site (R11/R15
// failure mode). off = LDS byte offset (low 32b of flat shared pointer;
// gfx9+ shared aperture is 4GiB-aligned).
static __device__ __forceinline__ v4f ds_load128(unsigned off) {
    v4f d;
    asm volatile("ds_read_b128 %0, %1" : "=v"(d) : "v"(off));
    return d;
}

// identical FMA chain in scan and rescan -> bit-exact equality
#define CHAIN4(T, MX, MY, MZ) \
    fmaf(MX, (T)[0], fmaf(MY, (T)[1], fmaf(MZ, (T)[2], (T)[3])))
#define CHAINF(T, MX, MY, MZ) \
    fmaf(MX, (T).x, fmaf(MY, (T).y, fmaf(MZ, (T).z, (T).w)))

// ---------------- pass 1: asm-pipelined chunked min3 argmin -----------------
__global__ __launch_bounds__(TPB, 4) void nn_min_kernel(
    const float* __restrict__ noisy, const float* __restrict__ clean,
    const float* __restrict__ seeds, const float* __restrict__ stds,
    const float* __restrict__ disp,  const float* __restrict__ noise,
    unsigned long long* __restrict__ keys)
{
    __shared__ float4 TS[NCHUNK][CHP];

    const int tid   = threadIdx.x;
    const int b     = blockIdx.y;
    const int mod   = blockIdx.z >> 4;
    const int sl    = blockIdx.z & 15;
    const int mbase = sl * SLICE_M;
    const int nb    = blockIdx.x * QPB + tid;

    const float sx = seeds[b * 3 + 0];
    const float sy = seeds[b * 3 + 1];
    const float sz = seeds[b * 3 + 2];
    float nstd = 0.0f;
    if (mod == 0) nstd = stds[b] * 0.25f;
    else if (mod == 1) nstd = stds[b] * 0.0625f;
    const bool nt = (mod < 2);

    // stage this 288-target slice
    for (int k = tid; k < SLICE_M; k += TPB) {
        const int m = mbase + k;
        const size_t oc = ((size_t)b * MM + m) * 3;
        float tx = clean[oc + 0] - sx;
        float ty = clean[oc + 1] - sy;
        float tz = clean[oc + 2] - sz;
        if (nt) {
            const size_t on = (((size_t)mod * BB + b) * MM + m) * 3;
            tx = fmaf(noise[on + 0], nstd, tx);
            ty = fmaf(noise[on + 1], nstd, ty);
            tz = fmaf(noise[on + 2], nstd, tz);
        }
        const float tw = fmaf(tx, tx, fmaf(ty, ty, tz * tz));
        TS[k >> 4][k & 15] = make_float4(tx, ty, tz, tw);
    }

    // ---- 8 queries, named scalars only ----
    float m2x0, m2y0, m2z0, m2x1, m2y1, m2z1, m2x2, m2y2, m2z2, m2x3, m2y3, m2z3;
    float m2x4, m2y4, m2z4, m2x5, m2y5, m2z5, m2x6, m2y6, m2z6, m2x7, m2y7, m2z7;

#define QSETUP(K, MX, MY, MZ) do {                                        \
        const int n = nb + (K) * TPB;                                     \
        const size_t o0 = ((size_t)b * NN + n) * 3;                       \
        float qx = noisy[o0 + 0] - sx;                                    \
        float qy = noisy[o0 + 1] - sy;                                    \
        float qz = noisy[o0 + 2] - sz;                                    \
        for (int j = 0; j < mod; ++j) {                                   \
            const size_t o = (((size_t)j * BB + b) * NN + n) * 3;         \
            qx += disp[o + 0]; qy += disp[o + 1]; qz += disp[o + 2];      \
        }                                                                 \
        MX = -2.0f * qx; MY = -2.0f * qy; MZ = -2.0f * qz;                \
    } while (0)

    QSETUP(0, m2x0, m2y0, m2z0); QSETUP(1, m2x1, m2y1, m2z1);
    QSETUP(2, m2x2, m2y2, m2z2); QSETUP(3, m2x3, m2y3, m2z3);
    QSETUP(4, m2x4, m2y4, m2z4); QSETUP(5, m2x5, m2y5, m2z5);
    QSETUP(6, m2x6, m2y6, m2z6); QSETUP(7, m2x7, m2y7, m2z7);
#undef QSETUP

    __syncthreads();

    float bb0 = INFINITY, bb1 = INFINITY, bb2 = INFINITY, bb3 = INFINITY;
    float bb4 = INFINITY, bb5 = INFINITY, bb6 = INFINITY, bb7 = INFINITY;
    int cc0 = 0, cc1 = 0, cc2 = 0, cc3 = 0, cc4 = 0, cc5 = 0, cc6 = 0, cc7 = 0;

    const unsigned tsb = (unsigned)(unsigned long long)&TS[0][0];

    // prologue: 3 pairs (6 reads) in flight
    v4f A0 = ds_load128(tsb +  0), A1 = ds_load128(tsb + 16);
    v4f B0 = ds_load128(tsb + 32), B1 = ds_load128(tsb + 48);
    v4f C0 = ds_load128(tsb + 64), C1 = ds_load128(tsb + 80);

#define EVAL2_(T0, T1, MX, MY, MZ, A) do {                                \
        const float d0_ = CHAIN4(T0, MX, MY, MZ);                         \
        const float d1_ = CHAIN4(T1, MX, MY, MZ);                         \
        A = min3f(d0_, d1_, A);                                           \
    } while (0)

#define EVAL8(T0, T1) do {                                                \
        EVAL2_(T0, T1, m2x0, m2y0, m2z0, a0);                             \
        EVAL2_(T0, T1, m2x1, m2y1, m2z1, a1);                             \
        EVAL2_(T0, T1, m2x2, m2y2, m2z2, a2);                             \
        EVAL2_(T0, T1, m2x3, m2y3, m2z3, a3);                             \
        EVAL2_(T0, T1, m2x4, m2y4, m2z4, a4);                             \
        EVAL2_(T0, T1, m2x5, m2y5, m2z5, a5);                             \
        EVAL2_(T0, T1, m2x6, m2y6, m2z6, a6);                             \
        EVAL2_(T0, T1, m2x7, m2y7, m2z7, a7);                             \
    } while (0)

// rule #18: counted wait, then sched_barrier(0) so hipcc cannot hoist the
// register-only FMA chain above the wait; prefetch after EVAL (WAR-ordered).
#define STEP(S0, S1, PIDX) do {                                           \
        asm volatile("s_waitcnt lgkmcnt(4)" ::: "memory");                \
        __builtin_amdgcn_sched_barrier(0);                                \
        EVAL8(S0, S1);                                                    \
        int pp_ = (PIDX); pp_ = pp_ < TOTP ? pp_ : TOTP - 1;              \
        const unsigned o_ = tsb +                                         \
            (unsigned)((pp_ >> 3) * (CHP * 16) + (pp_ & 7) * 32);         \
        S0 = ds_load128(o_); S1 = ds_load128(o_ + 16);                    \
    } while (0)

#define RESETA() do { a0 = a1 = a2 = a3 = a4 = a5 = a6 = a7 = INFINITY; } while (0)

#define CUPD1(A, BV, CV, CI) do {                                         \
        const bool c_ = (A) < (BV);                                       \
        BV = c_ ? (A) : (BV);                                             \
        CV = c_ ? (CI) : (CV);                                            \
    } while (0)

#define CUPD8(CI) do {                                                    \
        const int ci_ = (CI);                                             \
        CUPD1(a0, bb0, cc0, ci_); CUPD1(a1, bb1, cc1, ci_);               \
        CUPD1(a2, bb2, cc2, ci_); CUPD1(a3, bb3, cc3, ci_);               \
        CUPD1(a4, bb4, cc4, ci_); CUPD1(a5, bb5, cc5, ci_);               \
        CUPD1(a6, bb6, cc6, ci_); CUPD1(a7, bb7, cc7, ci_);               \
    } while (0)

    int pb = 0;
    #pragma unroll 1
    for (int sc = 0; sc < NSUP; ++sc) {
        float a0, a1, a2, a3, a4, a5, a6, a7;
        // chunk 3sc+0: slots 0,1,2,0,1,2,0,1
        RESETA();
        STEP(A0, A1, pb + 3);  STEP(B0, B1, pb + 4);  STEP(C0, C1, pb + 5);
        STEP(A0, A1, pb + 6);  STEP(B0, B1, pb + 7);  STEP(C0, C1, pb + 8);
        STEP(A0, A1, pb + 9);  STEP(B0, B1, pb + 10);
        CUPD8(3 * sc);
        // chunk 3sc+1: slots 2,0,1,2,0,1,2,0
        RESETA();
        STEP(C0, C1, pb + 11); STEP(A0, A1, pb + 12); STEP(B0, B1, pb + 13);
        STEP(C0, C1, pb + 14); STEP(A0, A1, pb + 15); STEP(B0, B1, pb + 16);
        STEP(C0, C1, pb + 17); STEP(A0, A1, pb + 18);
        CUPD8(3 * sc + 1);
        // chunk 3sc+2: slots 1,2,0,1,2,0,1,2
        RESETA();
        STEP(B0, B1, pb + 19); STEP(C0, C1, pb + 20); STEP(A0, A1, pb + 21);
        STEP(B0, B1, pb + 22); STEP(C0, C1, pb + 23); STEP(A0, A1, pb + 24);
        STEP(B0, B1, pb + 25); STEP(C0, C1, pb + 26);
        CUPD8(3 * sc + 2);
        pb += 24;
    }
    asm volatile("s_waitcnt lgkmcnt(0)" ::: "memory");

    unsigned long long* __restrict__ kslice = keys + (size_t)sl * QCOUNT
                                            + (((size_t)mod * BB + b) * NN);

    // rescan winning chunk (backward overwrite -> first match), pack, store
#define FINQ(K, MX, MY, MZ, BV, CV) do {                                  \
        int im = 0;                                                       \
        for (int u = CH - 1; u >= 0; --u) {                               \
            const float4 t = TS[CV][u];                                   \
            const float d = CHAINF(t, MX, MY, MZ);                        \
            im = (d == (BV)) ? ((CV) * CH + u) : im;                      \
        }                                                                 \
        const float q2 = 0.25f * fmaf(MX, MX, fmaf(MY, MY, (MZ) * (MZ)));\
        const float f = (BV) + q2 + 8.0f;                                 \
        const unsigned long long key =                                    \
            ((unsigned long long)__float_as_uint(f) << 32) |              \
            (unsigned int)(mbase + im);                                   \
        kslice[nb + (K) * TPB] = key;                                     \
    } while (0)

    FINQ(0, m2x0, m2y0, m2z0, bb0, cc0);
    FINQ(1, m2x1, m2y1, m2z1, bb1, cc1);
    FINQ(2, m2x2, m2y2, m2z2, bb2, cc2);
    FINQ(3, m2x3, m2y3, m2z3, bb3, cc3);
    FINQ(4, m2x4, m2y4, m2z4, bb4, cc4);
    FINQ(5, m2x5, m2y5, m2z5, bb5, cc5);
    FINQ(6, m2x6, m2y6, m2z6, bb6, cc6);
    FINQ(7, m2x7, m2y7, m2z7, bb7, cc7);
#undef FINQ
}

// ---------------- pass 2: combine slices, unpack winner, loss ---------------
__global__ __launch_bounds__(TPB) void nn_loss_pass2(
    const float* __restrict__ noisy, const float* __restrict__ clean,
    const float* __restrict__ seeds, const float* __restrict__ stds,
    const float* __restrict__ disp,  const float* __restrict__ noise,
    const unsigned long long* __restrict__ keys,
    float* __restrict__ partials)
{
    __shared__ float red[TPB / 64];
    const int tid = threadIdx.x;
    const int b   = blockIdx.y;
    const int mod = blockIdx.z;
    const int n   = blockIdx.x * TPB + tid;

    const float sx = seeds[b * 3 + 0];
    const float sy = seeds[b * 3 + 1];
    const float sz = seeds[b * 3 + 2];
    float nstd = 0.0f;
    if (mod == 0) nstd = stds[b] * 0.25f;
    else if (mod == 1) nstd = stds[b] * 0.0625f;

    float qx = noisy[((size_t)b * NN + n) * 3 + 0] - sx;
    float qy = noisy[((size_t)b * NN + n) * 3 + 1] - sy;
    float qz = noisy[((size_t)b * NN + n) * 3 + 2] - sz;
    for (int j = 0; j < mod; ++j) {
        const size_t o = (((size_t)j * BB + b) * NN + n) * 3;
        qx += disp[o + 0]; qy += disp[o + 1]; qz += disp[o + 2];
    }
    const size_t od = (((size_t)mod * BB + b) * NN + n) * 3;
    const float dxp = disp[od + 0];
    const float dyp = disp[od + 1];
    const float dzp = disp[od + 2];

    const size_t q = (((size_t)mod * BB + b) * NN) + n;
    unsigned long long k = keys[q];
    #pragma unroll
    for (int s = 1; s < SLICES; ++s) {
        const unsigned long long v = keys[(size_t)s * QCOUNT + q];
        k = v < k ? v : k;
    }
    const unsigned gidx = (unsigned)(k & 0xFFFFFFFFull);

    const size_t oc = ((size_t)b * MM + gidx) * 3;
    float tx = clean[oc + 0] - sx;
    float ty = clean[oc + 1] - sy;
    float tz = clean[oc + 2] - sz;
    if (mod < 2) {
        const size_t on = (((size_t)mod * BB + b) * MM + gidx) * 3;
        tx = fmaf(noise[on + 0], nstd, tx);
        ty = fmaf(noise[on + 1], nstd, ty);
        tz = fmaf(noise[on + 2], nstd, tz);
    }
    const float ex = dxp - (tx - qx);
    const float ey = dyp - (ty - qy);
    const float ez = dzp - (tz - qz);
    float v = fmaf(ex, ex, fmaf(ey, ey, ez * ez));

    for (int o = 32; o; o >>= 1) v += __shfl_down(v, o);
    if ((tid & 63) == 0) red[tid >> 6] = v;
    __syncthreads();
    if (tid == 0) {
        const float s = red[0] + red[1] + red[2] + red[3];
        partials[(((size_t)mod * BB + b) * NXBLK2) + blockIdx.x] = s;
    }
}

__global__ void finalize_kernel(const float* __restrict__ partials, float* __restrict__ out) {
    float s = 0.0f;
    for (int k = threadIdx.x; k < NPART; k += 64) s += partials[k];
    for (int o = 32; o; o >>= 1) s += __shfl_down(s, o);
    if (threadIdx.x == 0) {
        out[0] = s * (1.0f / BB);
        out[1] = s * (1.0f / BB);
    }
}

// ---------------- monolithic dense fallback (2 KiB ws) ----------------------
#define TM 768
__global__ __launch_bounds__(TPB) void nn_loss_kernel(
    const float* __restrict__ noisy, const float* __restrict__ clean,
    const float* __restrict__ seeds, const float* __restrict__ stds,
    const float* __restrict__ disp,  const float* __restrict__ noise,
    float* __restrict__ partials)
{
    __shared__ float4 tgt[TM];
    __shared__ float red[TPB / 64];
    const int tid = threadIdx.x;
    const int b = blockIdx.y, mod = blockIdx.z;
    const int n = blockIdx.x * TPB + tid;
    const float sx = seeds[b*3+0], sy = seeds[b*3+1], sz = seeds[b*3+2];
    float qx = noisy[((size_t)b*NN+n)*3+0] - sx;
    float qy = noisy[((size_t)b*NN+n)*3+1] - sy;
    float qz = noisy[((size_t)b*NN+n)*3+2] - sz;
    for (int j = 0; j < mod; ++j) {
        const size_t o = (((size_t)j*BB + b)*NN + n)*3;
        qx += disp[o+0]; qy += disp[o+1]; qz += disp[o+2];
    }
    const size_t od = (((size_t)mod*BB + b)*NN + n)*3;
    const float dxp = disp[od+0], dyp = disp[od+1], dzp = disp[od+2];
    float nstd = 0.0f;
    if (mod == 0) nstd = stds[b]*0.25f; else if (mod == 1) nstd = stds[b]*0.0625f;
    const bool nt = (mod < 2);
    const float m2x = -2.0f*qx, m2y = -2.0f*qy, m2z = -2.0f*qz;
    float best = INFINITY; int bestm = 0;
    for (int mt = 0; mt < MM; mt += TM) {
        __syncthreads();
        for (int k = tid; k < TM; k += TPB) {
            const int m = mt + k;
            const size_t oc = ((size_t)b*MM + m)*3;
            float tx = clean[oc+0]-sx, ty = clean[oc+1]-sy, tz = clean[oc+2]-sz;
            if (nt) {
                const size_t on = (((size_t)mod*BB + b)*MM + m)*3;
                tx = fmaf(noise[on+0], nstd, tx);
                ty = fmaf(noise[on+1], nstd, ty);
                tz = fmaf(noise[on+2], nstd, tz);
            }
            tgt[k] = make_float4(tx, ty, tz, fmaf(tx,tx,fmaf(ty,ty,tz*tz)));
        }
        __syncthreads();
        #pragma unroll 8
        for (int k = 0; k < TM; ++k) {
            const float4 t = tgt[k];
            const float d2 = fmaf(m2x, t.x, fmaf(m2y, t.y, fmaf(m2z, t.z, t.w)));
            if (d2 < best) { best = d2; bestm = mt + k; }
        }
    }
    const size_t oc = ((size_t)b*MM + bestm)*3;
    float tx = clean[oc+0]-sx, ty = clean[oc+1]-sy, tz = clean[oc+2]-sz;
    if (nt) {
        const size_t on = (((size_t)mod*BB + b)*MM + bestm)*3;
        tx = fmaf(noise[on+0], nstd, tx);
        ty = fmaf(noise[on+1], nstd, ty);
        tz = fmaf(noise[on+2], nstd, tz);
    }
    const float ex = dxp - (tx - qx), ey = dyp - (ty - qy), ez = dzp - (tz - qz);
    float v = fmaf(ex, ex, fmaf(ey, ey, ez*ez));
    for (int o = 32; o; o >>= 1) v += __shfl_down(v, o);
    if ((tid & 63) == 0) red[tid >> 6] = v;
    __syncthreads();
    if (tid == 0)
        partials[(((size_t)mod*BB + b)*NXBLK2) + blockIdx.x] = red[0]+red[1]+red[2]+red[3];
}

extern "C" void kernel_launch(void* const* d_in, const int* in_sizes, int n_in,
                              void* d_out, int out_size, void* d_ws, size_t ws_size,
                              hipStream_t stream) {
    const float* noisy = (const float*)d_in[0];
    const float* clean = (const float*)d_in[1];
    const float* seeds = (const float*)d_in[2];
    const float* stds  = (const float*)d_in[3];
    const float* disp  = (const float*)d_in[4];
    const float* noise = (const float*)d_in[5];
    float* out = (float*)d_out;

    if (ws_size >= WS_NEED) {
        unsigned long long* keys = (unsigned long long*)d_ws;
        float* partials = (float*)((char*)d_ws + KEYB);
        dim3 g1(NXB, BB, NMOD * SLICES);
        nn_min_kernel<<<g1, TPB, 0, stream>>>(noisy, clean, seeds, stds, disp, noise, keys);
        dim3 g2(NXBLK2, BB, NMOD);
        nn_loss_pass2<<<g2, TPB, 0, stream>>>(noisy, clean, seeds, stds, disp, noise, keys, partials);
        finalize_kernel<<<1, 64, 0, stream>>>(partials, out);
    } else {
        float* partials = (float*)d_ws;
        dim3 grid(NXBLK2, BB, NMOD);
        nn_loss_kernel<<<grid, TPB, 0, stream>>>(noisy, clean, seeds, stds, disp, noise, partials);
        finalize_kernel<<<1, 64, 0, stream>>>(partials, out);
    }
}